// Round 5
// baseline (207.996 us; speedup 1.0000x reference)
//
#include <hip/hip_runtime.h>

// VACF via banded-Gram MFMA, round 14.
// G[t] = sum_i X[i][:] . X[i+t][:]  (t=0..99), X = [T=10000, C=3000] fp32.
//
// R13 post-mortem: both kernels < top-5 cutoff; timed window = 70us poison
// fill + relayout ~62 + main ~66 + ~5. Cross-round invariant: R11/R12 main
// both cost ~4000 cyc per double-barrier iteration regardless of bytes
// (staging BW 2.2->1.4 TB/s: contiguity cut bytes, not time/iter) => main
// is a depth-1-prefetch convoy: ~4k-cyc gload_lds completion vs ~500-cyc
// iteration compute, unhideable at 2.5 lockstep blocks/CU. R14:
//  - main: SINGLE-SHOT staging. KSPLIT 16->32, CPB 6->3: block stages its
//    whole 3-chunk set (73.7KB LDS, 18 gload/wave, one vmcnt(0)+barrier),
//    then computes barrier-free. Staged bytes unchanged (94.4MB). 1280
//    blocks = 5/CU, 2 co-resident -> partner-block compute hides latency.
//  - relayout: ~62us ~= dirty-victim wall (480MB poison fill leaves L3
//    dirty; X's 120MB cold reads evict ~120MB writebacks). X has zero
//    reuse -> __builtin_nontemporal_load (no L3 allocate) + unguarded
//    interior fast path.
// Y layout (chunk-major 64B granules, sigma(r)=(r>>1)&3 baked) unchanged.

#define T_DIM 10000
#define C_DIM 3000
#define W 100

// relayout geometry
#define CHUNKS 96            // 32-col chunks (3000 -> 94 -> pad to 96)
#define RPAD 10368           // padded rows (max staged row 9984+384)
#define GRAN 64              // bytes per (chunk,row) granule = 32 bf16
#define PITCH 576            // relayout LDS tile pitch (bytes); 144w==16 mod 32
#define YOFF 4096            // Y offset in ws; partial[] at ws+0
#define WS_NEED (YOFF + (size_t)CHUNKS * RPAD * GRAN)

// main kernel geometry
#define MA 256               // A rows per block
#define NA 16                // A subblocks of 16
#define SROWS 384            // staged rows (A + band to subblock 23)
#define NBB 40               // 40*256 = 10240 >= 10000
#define KSPLIT 32            // k-slices of CPB chunks
#define CPB 3                // 32*3 = 96 chunks
#define CTILE (SROWS * GRAN) // 24576 B per chunk tile
#define NPART 8

// fallback (R10) geometry
#define FB_MA 112
#define FB_NA 7
#define FB_SROWS 224
#define FB_NBB 90
#define FB_KSPLIT 24
#define FB_CPB 4
#define FB_KB 32
#define FB_LPAD 34

typedef __attribute__((ext_vector_type(8))) short short8;    // 8 bf16
typedef __attribute__((ext_vector_type(4))) short short4v;   // 4 bf16
typedef __attribute__((ext_vector_type(4))) float float4v;
typedef __attribute__((ext_vector_type(4))) unsigned int uint4v;

__device__ __forceinline__ short f2bf(float f) {   // RNE fp32->bf16 (finite)
    unsigned u = __float_as_uint(f);
    u += 0x7fffu + ((u >> 16) & 1u);
    return (short)(u >> 16);
}

__device__ __forceinline__ void gload_lds16(const char* src, char* dst) {
    __builtin_amdgcn_global_load_lds(
        (const __attribute__((address_space(1))) unsigned int*)src,
        (__attribute__((address_space(3))) unsigned int*)dst, 16, 0, 0);
}

__device__ __forceinline__ float4v ntload4(const float* p) {
    return __builtin_nontemporal_load((const float4v*)p);
}

// ---------------------------------------------------------------------------
// Kernel 1: X fp32 row-major -> Y bf16 chunk-major with baked sigma swizzle.
// Granule (c, r) holds cols 32c + 8*(p ^ sigma(r)) .. +7 at slot position p,
// sigma(r) = (r>>1)&3. Zero outside [0,10000) x [0,3000).
// Block: 64 rows x 256 cols.
// ---------------------------------------------------------------------------
__global__ __launch_bounds__(256)
void vacf_relayout(const float* __restrict__ X, char* __restrict__ Y) {
    __shared__ __align__(16) char tile[64 * PITCH];   // 36.9 KB
    const int tid = threadIdx.x;
    const int l   = tid & 63;
    const int w   = tid >> 6;
    const int bc  = blockIdx.x % 12;       // col-group (256 cols)
    const int br  = blockIdx.x / 12;       // row-group (64 rows)
    const int r0  = br * 64;
    const int c0  = bc * 256;

    // phase 1: coalesced read of X[64r x 256c], convert, swizzled LDS store.
    // wave w, iter k: row rl = k*4 + w, lane covers cols 4l..4l+3 (1KB/wave).
    const bool interior = (r0 + 64 <= T_DIM) && (c0 + 256 <= C_DIM);
    if (interior) {
        #pragma unroll
        for (int k = 0; k < 16; ++k) {
            const int rl  = k * 4 + w;
            const int col = l * 4;
            const float4v v = ntload4(X + (size_t)(r0 + rl) * C_DIM + c0 + col);
            short4v o;
            o[0] = f2bf(v[0]); o[1] = f2bf(v[1]); o[2] = f2bf(v[2]); o[3] = f2bf(v[3]);
            const int cc = col >> 5, p = (col >> 3) & 3, sub = col & 7;
            const int ps = p ^ ((rl >> 1) & 3);
            *(short4v*)&tile[rl * PITCH + cc * 64 + ps * 16 + sub * 2] = o;
        }
    } else {
        #pragma unroll
        for (int k = 0; k < 16; ++k) {
            const int rl  = k * 4 + w;
            const int col = l * 4;
            const int row = r0 + rl;
            float4v v = {0.f, 0.f, 0.f, 0.f};
            if (row < T_DIM && c0 + col + 4 <= C_DIM)   // 3000%4==0: no straddle
                v = *(const float4v*)(X + (size_t)row * C_DIM + c0 + col);
            short4v o;
            o[0] = f2bf(v[0]); o[1] = f2bf(v[1]); o[2] = f2bf(v[2]); o[3] = f2bf(v[3]);
            const int cc = col >> 5, p = (col >> 3) & 3, sub = col & 7;
            const int ps = p ^ ((rl >> 1) & 3);
            *(short4v*)&tile[rl * PITCH + cc * 64 + ps * 16 + sub * 2] = o;
        }
    }
    __syncthreads();

    // phase 2: wave w owns rows [16w, 16w+16); lane (rl = 16w + l>>2, q = l&3)
    // -> every wave-store is a fully contiguous 1KB span of Y.
    const int rl = 16 * w + (l >> 2);
    const int q  = l & 3;
    const char* s = &tile[rl * PITCH + q * 16];
    #pragma unroll
    for (int cc = 0; cc < 8; ++cc) {
        char* dst = Y + ((size_t)(bc * 8 + cc) * RPAD + r0 + rl) * GRAN + q * 16;
        *(uint4v*)dst = *(const uint4v*)(s + cc * 64);
    }
}

// ---------------------------------------------------------------------------
// Kernel 2: banded-Gram MFMA from chunk-major Y. Single-shot staging:
// stage all 3 chunks (18 x 1-KiB DMA per wave), one vmcnt(0) + barrier,
// then barrier-free compute. 2 blocks/CU co-resident.
// ---------------------------------------------------------------------------
__global__ __launch_bounds__(256, 2)
void vacf_main(const char* __restrict__ Y, float* __restrict__ partial) {
    const int tid  = threadIdx.x;
    const int lane = tid & 63;
    const int wv   = tid >> 6;
    const int xcd  = blockIdx.x & 7;
    const int j    = blockIdx.x >> 3;          // 0..159, consecutive on XCD
    const int ksix = xcd + 8 * (j / NBB);      // k-slice 0..31, XCD-constant/sweep
    const int bb   = j % NBB;                  // row-block, consecutive on XCD
    const int i0   = bb * MA;                  // mult of 256 -> sigma local

    __shared__ __align__(16) char lds[CPB * CTILE];   // 73.7 KB
    __shared__ float bins[W];
    if (tid < W) bins[tid] = 0.f;

    const int n    = lane & 15;
    const int quad = lane >> 4;
    const int d0   = 2 * wv;                   // wave's diagonal pair d0, d0+1
    // fragment base: row n, slot quad ^ sigma(n); row R=16s+n adds s*1024.
    const int fragoff = n * 64 + ((quad ^ ((n >> 1) & 3)) << 4);
    const int lr16 = lane * 16;

    // stage: wave wv owns rows [wv*96, wv*96+96) of each of the 3 chunks.
    #pragma unroll
    for (int cc = 0; cc < CPB; ++cc) {
        const char* sb = Y + ((size_t)(ksix * CPB + cc) * RPAD + i0 + wv * 96) * GRAN;
        char* db = lds + cc * CTILE + wv * 96 * GRAN;
        #pragma unroll
        for (int m = 0; m < 6; ++m)
            gload_lds16(sb + m * 1024 + lr16, db + m * 1024);
    }
    asm volatile("s_waitcnt vmcnt(0)" ::: "memory");
    __builtin_amdgcn_s_barrier();              // tile ready (and bins init)

    float4v acc0 = {0.f, 0.f, 0.f, 0.f};
    float4v acc1 = {0.f, 0.f, 0.f, 0.f};

    #pragma unroll
    for (int cc = 0; cc < CPB; ++cc) {
        const char* lb = lds + cc * CTILE + fragoff;
        short8 fbp = *(const short8*)(lb + d0 * 1024);       // B subblock d0
        #pragma unroll
        for (int a = 0; a < NA; ++a) {
            const short8 fav = *(const short8*)(lb + a * 1024);
            const short8 fbn = *(const short8*)(lb + (d0 + a + 1) * 1024);
            acc0 = __builtin_amdgcn_mfma_f32_16x16x32_bf16(fav, fbp, acc0, 0, 0, 0);
            acc1 = __builtin_amdgcn_mfma_f32_16x16x32_bf16(fav, fbn, acc1, 0, 0, 0);
            fbp = fbn;
        }
    }

    // epilogue: D[m][n] of diagonal d -> lag t = 16d + n - m  (m = quad*4 + p)
    #pragma unroll
    for (int p = 0; p < 4; ++p) {
        const int m  = quad * 4 + p;
        const int t0 = 16 * d0 + n - m;
        if (t0 >= 0 && t0 < W) atomicAdd(&bins[t0], acc0[p]);
        const int t1 = t0 + 16;
        if (t1 >= 0 && t1 < W) atomicAdd(&bins[t1], acc1[p]);
    }
    __syncthreads();
    if (tid < W) atomicAdd(&partial[xcd * W + tid], bins[tid]);
}

// ---------------------------------------------------------------------------
// Fallback (ws too small): R10 register-staging kernel, proven correct.
// ---------------------------------------------------------------------------
__global__ __launch_bounds__(256, 2)
void vacf_fb(const float* __restrict__ X, float* __restrict__ partial) {
    const int tid  = threadIdx.x;
    const int lane = tid & 63;
    const int wv   = tid >> 6;
    const int xcd  = blockIdx.x & 7;
    const int j    = blockIdx.x >> 3;
    const int ksix = xcd + 8 * (j / FB_NBB);
    const int bb   = j % FB_NBB;
    const int i0   = bb * FB_MA;
    const int ks   = ksix * (FB_CPB * FB_KB);
    const int ke   = (ks + FB_CPB * FB_KB < C_DIM) ? (ks + FB_CPB * FB_KB) : C_DIM;
    const int nit  = (ke - ks + FB_KB - 1) / FB_KB;

    __shared__ short buf[FB_SROWS * FB_LPAD];
    __shared__ float bins[W];
    if (tid < W) bins[tid] = 0.f;

    const int cp = tid & 7;
    const int r0 = tid >> 3;
    const int n    = lane & 15;
    const int quad = lane >> 4;
    const int d0   = 2 * wv;
    const short* fragbase = &buf[n * FB_LPAD + quad * 8];

    float4v acc0 = {0.f, 0.f, 0.f, 0.f};
    float4v acc1 = {0.f, 0.f, 0.f, 0.f};
    float4v pf[FB_NA];

    {
        #pragma unroll
        for (int s = 0; s < FB_NA; ++s) {
            const int row = i0 + r0 + 32 * s;
            const int col = ks + 4 * cp;
            pf[s] = (row < T_DIM) ? *(const float4v*)(X + (size_t)row * C_DIM + col)
                                  : (float4v){0.f, 0.f, 0.f, 0.f};
        }
    }

    #pragma unroll 1
    for (int it = 0; it < nit; ++it) {
        __syncthreads();
        #pragma unroll
        for (int s = 0; s < FB_NA; ++s) {
            short4v o;
            o[0] = f2bf(pf[s][0]); o[1] = f2bf(pf[s][1]);
            o[2] = f2bf(pf[s][2]); o[3] = f2bf(pf[s][3]);
            *(short4v*)&buf[(r0 + 32 * s) * FB_LPAD + 4 * cp] = o;
        }
        __syncthreads();

        if (it + 1 < nit) {
            const int k0 = ks + (it + 1) * FB_KB;
            const bool kfull = (k0 + FB_KB <= ke);
            #pragma unroll
            for (int s = 0; s < FB_NA; ++s) {
                const int row = i0 + r0 + 32 * s;
                const int col = k0 + 4 * cp;
                if ((row < T_DIM) & kfull) {
                    pf[s] = *(const float4v*)(X + (size_t)row * C_DIM + col);
                } else {
                    #pragma unroll
                    for (int e = 0; e < 4; ++e)
                        pf[s][e] = (row < T_DIM && col + e < ke)
                                     ? X[(size_t)row * C_DIM + col + e] : 0.f;
                }
            }
        }

        short8 fa[FB_NA], fb[8];
        #pragma unroll
        for (int a = 0; a < FB_NA; ++a)
            fa[a] = *(const short8*)(fragbase + 16 * a * FB_LPAD);
        #pragma unroll
        for (int u = 0; u < 8; ++u)
            fb[u] = *(const short8*)(fragbase + 16 * (d0 + u) * FB_LPAD);

        #pragma unroll
        for (int a = 0; a < FB_NA; ++a) {
            acc0 = __builtin_amdgcn_mfma_f32_16x16x32_bf16(fa[a], fb[a],     acc0, 0, 0, 0);
            acc1 = __builtin_amdgcn_mfma_f32_16x16x32_bf16(fa[a], fb[a + 1], acc1, 0, 0, 0);
        }
    }

    #pragma unroll
    for (int p = 0; p < 4; ++p) {
        const int m  = quad * 4 + p;
        const int t0 = 16 * d0 + n - m;
        if (t0 >= 0 && t0 < W) atomicAdd(&bins[t0], acc0[p]);
        const int t1 = t0 + 16;
        if (t1 >= 0 && t1 < W) atomicAdd(&bins[t1], acc1[p]);
    }
    __syncthreads();
    if (tid < W) atomicAdd(&partial[xcd * W + tid], bins[tid]);
}

__global__ void vacf_scale(const float* __restrict__ partial, float* __restrict__ out) {
    int t = threadIdx.x;
    if (t < W) {
        float s = 0.f;
        #pragma unroll
        for (int b = 0; b < NPART; ++b) s += partial[b * W + t];
        out[t] = s / ((float)(T_DIM - t) * (float)C_DIM);
    }
}

extern "C" void kernel_launch(void* const* d_in, const int* in_sizes, int n_in,
                              void* d_out, int out_size, void* d_ws, size_t ws_size,
                              hipStream_t stream) {
    const float* X = (const float*)d_in[0];
    float* out = (float*)d_out;
    float* ws  = (float*)d_ws;

    hipMemsetAsync(ws, 0, NPART * W * sizeof(float), stream);
    if (ws_size >= WS_NEED) {
        char* Y = (char*)d_ws + YOFF;
        vacf_relayout<<<(RPAD / 64) * 12, 256, 0, stream>>>(X, Y);
        vacf_main<<<NBB * KSPLIT, 256, 0, stream>>>(Y, ws);
    } else {
        vacf_fb<<<FB_NBB * FB_KSPLIT, 256, 0, stream>>>(X, ws);
    }
    vacf_scale<<<1, 128, 0, stream>>>(ws, out);
}